// Round 1
// baseline (734.678 us; speedup 1.0000x reference)
//
#include <hip/hip_runtime.h>
#include <hip/hip_bf16.h>

typedef __attribute__((ext_vector_type(4))) float f32x4;
typedef __attribute__((ext_vector_type(8))) short s16x8;

#define NB 8
#define NC 256
#define NHW 4096
#define TOTHW (NB * NHW)

// ---------------------------------------------------------------------------
// Kernel 1: channel-L2 normalize + transpose [B][C][HW] -> [B][HW][C] + bf16
// hi/lo split.  64 hw positions per block, 256 threads.
// ---------------------------------------------------------------------------
__global__ __launch_bounds__(256) void norm_tr_kernel(
    const float* __restrict__ x,
    unsigned short* __restrict__ hi,
    unsigned short* __restrict__ lo) {
  __shared__ float tile[NC][65];   // +1 pad: phase-2 strided reads ~8-way, ok
  __shared__ float partial[4][64];
  __shared__ float scale[64];

  const int t = threadIdx.x;
  const int b = blockIdx.y;
  const int hw0 = blockIdx.x * 64;
  const float* xb = x + (size_t)b * NC * NHW + hw0;

  // load 256 x 64 fp32 tile, coalesced float4
#pragma unroll
  for (int i = 0; i < 16; ++i) {
    const int idx4 = t + i * 256;          // 0..4095
    const int c = idx4 >> 4;               // 0..255
    const int h4 = (idx4 & 15) << 2;       // 0..60
    const f32x4 v = *reinterpret_cast<const f32x4*>(xb + (size_t)c * NHW + h4);
    tile[c][h4 + 0] = v.x;
    tile[c][h4 + 1] = v.y;
    tile[c][h4 + 2] = v.z;
    tile[c][h4 + 3] = v.w;
  }
  __syncthreads();

  // sum of squares over channels: 4 partial groups of 64 channels
  {
    const int hw = t & 63, cg = t >> 6;
    float s = 0.f;
#pragma unroll
    for (int j = 0; j < 64; ++j) {
      const float v = tile[cg * 64 + j][hw];
      s = fmaf(v, v, s);
    }
    partial[cg][hw] = s;
  }
  __syncthreads();
  if (t < 64) {
    const float tot = partial[0][t] + partial[1][t] + partial[2][t] + partial[3][t];
    scale[t] = 1.0f / fmaxf(sqrtf(tot), 1e-12f);
  }
  __syncthreads();

  // transpose + scale + bf16 hi/lo split, 16B vector stores
#pragma unroll
  for (int i = 0; i < 8; ++i) {
    const int ch = t + i * 256;            // 0..2047
    const int hw = ch >> 5;                // 0..63
    const int c0 = (ch & 31) << 3;         // 0..248
    const float s = scale[hw];
    s16x8 hv, lv;
#pragma unroll
    for (int j = 0; j < 8; ++j) {
      const float v = tile[c0 + j][hw] * s;
      const __hip_bfloat16 h = __float2bfloat16(v);
      const float r = v - __bfloat162float(h);
      const __hip_bfloat16 l = __float2bfloat16(r);
      hv[j] = __builtin_bit_cast(short, h);
      lv[j] = __builtin_bit_cast(short, l);
    }
    const size_t row = (size_t)b * NHW + hw0 + hw;
    *reinterpret_cast<s16x8*>(hi + row * NC + c0) = hv;
    *reinterpret_cast<s16x8*>(lo + row * NC + c0) = lv;
  }
}

// ---------------------------------------------------------------------------
// Kernel 2: per-batch GEMM  out[b][m][n] = sum_k A[b][m][k] * Bm[b][n][k]
// A = cur (hi+lo), Bm = ref (hi+lo);  3-term bf16x2 product into fp32 acc.
// 128x128 tile, BK=64, 4 waves (2x2), each wave 64x64 via 4x4 16x16x32 frags.
// LDS: 4 tiles x [128][64] bf16 = 64 KB, XOR-swizzled (byte ^= (row&7)<<4),
// staged linearly via global_load_lds width-16 from inverse-swizzled source.
// ---------------------------------------------------------------------------
#define AHI 0
#define ALO 16384
#define BHI 32768
#define BLO 49152

__device__ inline void gload16(const void* g, void* l) {
  __builtin_amdgcn_global_load_lds(
      (const __attribute__((address_space(1))) void*)g,
      (__attribute__((address_space(3))) void*)l, 16, 0, 0);
}

__global__ __launch_bounds__(256) void gemm_kernel(
    const unsigned short* __restrict__ curHi,
    const unsigned short* __restrict__ curLo,
    const unsigned short* __restrict__ refHi,
    const unsigned short* __restrict__ refLo,
    float* __restrict__ out) {
  __shared__ char lds[65536];

  const int t = threadIdx.x;
  const int bb = blockIdx.z;
  const int n0 = blockIdx.x * 128;
  const int m0 = blockIdx.y * 128;

  // staging: thread t stages chunk q = i*256+t (16B each) of each tile.
  // physical row r = q>>3, slot s = q&7; source k-block = 8*(s ^ (r&7))
  // so that a swizzled read  byte = (r*128 + 2k) ^ ((r&7)<<4)  hits it.
  const int rb = t >> 3;                       // 0..31
  const int k0 = ((t & 7) ^ (rb & 7)) << 3;    // bf16 elems within row
  const unsigned short* gAh = curHi + ((size_t)bb * NHW + m0 + rb) * NC + k0;
  const unsigned short* gAl = curLo + ((size_t)bb * NHW + m0 + rb) * NC + k0;
  const unsigned short* gBh = refHi + ((size_t)bb * NHW + n0 + rb) * NC + k0;
  const unsigned short* gBl = refLo + ((size_t)bb * NHW + n0 + rb) * NC + k0;
  char* lDst = lds + t * 16;

  const int lane = t & 63;
  const int w = t >> 6;
  const int wm = (w >> 1) * 64;    // wave row offset in 128-tile
  const int wn = (w & 1) * 64;     // wave col offset
  const int lrow = lane & 15;
  const int lk = (lane >> 4) * 8;  // k-offset within 32-k fragment

  f32x4 acc[4][4];
#pragma unroll
  for (int i = 0; i < 4; ++i)
#pragma unroll
    for (int j = 0; j < 4; ++j) acc[i][j] = (f32x4)0.f;

  for (int kt = 0; kt < 4; ++kt) {
    const int ko = kt * 64;
#pragma unroll
    for (int i = 0; i < 4; ++i) {
      const size_t ro = (size_t)(i * 32) * NC + ko;
      gload16(gAh + ro, lDst + AHI + i * 4096);
      gload16(gAl + ro, lDst + ALO + i * 4096);
      gload16(gBh + ro, lDst + BHI + i * 4096);
      gload16(gBl + ro, lDst + BLO + i * 4096);
    }
    __syncthreads();

#pragma unroll
    for (int ks = 0; ks < 2; ++ks) {
      s16x8 ah[4], al[4], bh[4], bl[4];
      const int kb = (ks * 32 + lk) * 2;  // byte offset of k within row
#pragma unroll
      for (int f = 0; f < 4; ++f) {
        const int m = wm + f * 16 + lrow;
        const int offA = ((m << 7) + kb) ^ ((m & 7) << 4);
        ah[f] = *reinterpret_cast<const s16x8*>(lds + AHI + offA);
        al[f] = *reinterpret_cast<const s16x8*>(lds + ALO + offA);
        const int n = wn + f * 16 + lrow;
        const int offB = ((n << 7) + kb) ^ ((n & 7) << 4);
        bh[f] = *reinterpret_cast<const s16x8*>(lds + BHI + offB);
        bl[f] = *reinterpret_cast<const s16x8*>(lds + BLO + offB);
      }
#pragma unroll
      for (int fm = 0; fm < 4; ++fm)
#pragma unroll
        for (int fn = 0; fn < 4; ++fn) {
          acc[fm][fn] = __builtin_amdgcn_mfma_f32_16x16x32_bf16(
              ah[fm], bh[fn], acc[fm][fn], 0, 0, 0);
          acc[fm][fn] = __builtin_amdgcn_mfma_f32_16x16x32_bf16(
              ah[fm], bl[fn], acc[fm][fn], 0, 0, 0);
          acc[fm][fn] = __builtin_amdgcn_mfma_f32_16x16x32_bf16(
              al[fm], bh[fn], acc[fm][fn], 0, 0, 0);
        }
    }
    __syncthreads();
  }

  // epilogue: C/D layout col = lane&15, row = (lane>>4)*4 + reg
  float* op = out + ((size_t)bb * NHW + m0) * NHW + n0;
  const int orow0 = wm + ((lane >> 4) << 2);
  const int ocol = wn + lrow;
#pragma unroll
  for (int fm = 0; fm < 4; ++fm)
#pragma unroll
    for (int fn = 0; fn < 4; ++fn)
#pragma unroll
      for (int r = 0; r < 4; ++r)
        op[(size_t)(orow0 + fm * 16 + r) * NHW + (ocol + fn * 16)] =
            acc[fm][fn][r];
}

// ---------------------------------------------------------------------------
extern "C" void kernel_launch(void* const* d_in, const int* in_sizes, int n_in,
                              void* d_out, int out_size, void* d_ws,
                              size_t ws_size, hipStream_t stream) {
  const float* ref = (const float*)d_in[0];   // ref_features [8,256,64,64]
  const float* cur = (const float*)d_in[1];   // cur_features [8,256,64,64]
  float* out = (float*)d_out;                 // [8,64,64,64,64] fp32

  unsigned short* ws = (unsigned short*)d_ws;
  const size_t T = (size_t)NB * NHW * NC;     // 8,388,608 elems = 16 MB each
  unsigned short* refHi = ws;
  unsigned short* refLo = ws + T;
  unsigned short* curHi = ws + 2 * T;
  unsigned short* curLo = ws + 3 * T;

  dim3 ngrid(NHW / 64, NB);
  norm_tr_kernel<<<ngrid, 256, 0, stream>>>(ref, refHi, refLo);
  norm_tr_kernel<<<ngrid, 256, 0, stream>>>(cur, curHi, curLo);

  dim3 ggrid(NHW / 128, NHW / 128, NB);
  gemm_kernel<<<ggrid, 256, 0, stream>>>(curHi, curLo, refHi, refLo, out);
}